// Round 11
// baseline (551.819 us; speedup 1.0000x reference)
//
#include <hip/hip_runtime.h>

#define N_NODES 50000
#define N_EDGES 1600000
#define NB 128
#define GB 782          // ceil(N/64)
#define CAP 80                   // bucket slots per node; P(deg>80)~1e-17 (Poisson 32)
#define NODE_RANGE 6250          // N/8: dst-range per build sub-pass
#define EDGE_BLOCKS 6250         // N_EDGES/256
#define INIT_BLOCKS 32           // pooled init (NB*64 floats)

__device__ __forceinline__ unsigned short f2bf(float f) {
    unsigned u = __float_as_uint(f);
    unsigned r = (u + 0x7FFFu + ((u >> 16) & 1u)) >> 16;   // RNE
    return (unsigned short)r;
}
__device__ __forceinline__ float bflo(unsigned u) { return __uint_as_float(u << 16); }
__device__ __forceinline__ float bfhi(unsigned u) { return __uint_as_float(u & 0xFFFF0000u); }

// ---- Bucket-CSR build: 8 dst-range sub-passes (bid&7). ----
// Measured best (74us, probed: pass-count/width/locality). Range split keeps
// the ACTIVE csr store region ~1MB so 2B scattered stores write-combine
// before eviction. Tail blocks do pooled init. NO NT anywhere (R1: NT on
// scattered stores 1.6x worse; R10: NT bypasses L2 entirely on gfx950).
__global__ __launch_bounds__(256) void k_build(
    const int* __restrict__ src, const int* __restrict__ dst,
    int* __restrict__ cnt, unsigned short* __restrict__ csr_src,
    const float* __restrict__ vn_emb, float* __restrict__ pooled) {
    int bid = blockIdx.x;
    if (bid >= EDGE_BLOCKS * 8) {
        int t = (bid - EDGE_BLOCKS * 8) * 256 + threadIdx.x;
        pooled[t] = vn_emb[t & 63];
        return;
    }
    int range = bid & 7;
    int e = (bid >> 3) * 256 + threadIdx.x;
    int d = dst[e];
    if (d / NODE_RANGE != range) return;
    int pos = atomicAdd(&cnt[d], 1);
    if (pos < CAP) csr_src[(size_t)d * CAP + pos] = (unsigned short)src[e];
}

// Input linear fused with layer-0 "pre": h = x@W + b + vn_emb; out = h;
// rbuf = bf16(relu(h)) in HALF-TABLE layout [half][node][32] (each half
// 3.2MB, fits a 4MB per-XCD L2); pooled += segsum(h).
__global__ __launch_bounds__(256) void k_lin_pre(
    const float* __restrict__ in, const float* __restrict__ W,
    const float* __restrict__ bias, const float* __restrict__ vn_emb,
    const int* __restrict__ batch_id,
    float* __restrict__ h, float* __restrict__ out,
    unsigned short* __restrict__ rbuf, float* __restrict__ pooled) {
    __shared__ float sW[64 * 64];
    __shared__ float sIn[64 * 68];
    int tid = threadIdx.x;
    int row0 = blockIdx.x * 64;

    const float4* W4 = (const float4*)W;
#pragma unroll
    for (int i = 0; i < 4; ++i) ((float4*)sW)[tid + 256 * i] = W4[tid + 256 * i];
    const float4* in4 = (const float4*)in;
#pragma unroll
    for (int i = 0; i < 4; ++i) {
        int idx = tid + 256 * i;
        int r = idx >> 4, j = idx & 15;
        float4 val = make_float4(0.f, 0.f, 0.f, 0.f);
        if (row0 + r < N_NODES) val = in4[(size_t)(row0 + r) * 16 + j];
        ((float4*)(sIn + r * 68))[j] = val;
    }
    __syncthreads();

    int c4 = (tid & 15) * 4;
    int rl = (tid >> 4) * 4;
    float acc[4][4] = {{0.f}};
#pragma unroll 8
    for (int k = 0; k < 64; ++k) {
        float4 wv = *(const float4*)(sW + k * 64 + c4);
        float a0 = sIn[(rl + 0) * 68 + k];
        float a1 = sIn[(rl + 1) * 68 + k];
        float a2 = sIn[(rl + 2) * 68 + k];
        float a3 = sIn[(rl + 3) * 68 + k];
        acc[0][0] += a0 * wv.x; acc[0][1] += a0 * wv.y; acc[0][2] += a0 * wv.z; acc[0][3] += a0 * wv.w;
        acc[1][0] += a1 * wv.x; acc[1][1] += a1 * wv.y; acc[1][2] += a1 * wv.z; acc[1][3] += a1 * wv.w;
        acc[2][0] += a2 * wv.x; acc[2][1] += a2 * wv.y; acc[2][2] += a2 * wv.z; acc[2][3] += a2 * wv.w;
        acc[3][0] += a3 * wv.x; acc[3][1] += a3 * wv.y; acc[3][2] += a3 * wv.z; acc[3][3] += a3 * wv.w;
    }
    float shf[4];
#pragma unroll
    for (int j = 0; j < 4; ++j) shf[j] = bias[c4 + j] + vn_emb[c4 + j];

    int lane = tid & 63;
    int wave = tid >> 6;
    int wr0 = row0 + wave * 16;
    bool full = (wr0 + 15 < N_NODES);
    bool fast = full && (batch_id[wr0] == batch_id[wr0 + 15]);
    float4 pacc = make_float4(0.f, 0.f, 0.f, 0.f);
#pragma unroll
    for (int r = 0; r < 4; ++r) {
        int row = row0 + rl + r;
        if (row >= N_NODES) continue;
        float4 v;
        v.x = acc[r][0] + shf[0];
        v.y = acc[r][1] + shf[1];
        v.z = acc[r][2] + shf[2];
        v.w = acc[r][3] + shf[3];
        *(float4*)(h + (size_t)row * 64 + c4) = v;
        *(float4*)(out + (size_t)row * 64 + c4) = v;
        ushort4 rb;
        rb.x = f2bf(fmaxf(v.x, 0.f)); rb.y = f2bf(fmaxf(v.y, 0.f));
        rb.z = f2bf(fmaxf(v.z, 0.f)); rb.w = f2bf(fmaxf(v.w, 0.f));
        *(ushort4*)(rbuf + (size_t)(c4 >> 5) * ((size_t)N_NODES * 32)
                    + (size_t)row * 32 + (c4 & 31)) = rb;
        if (fast) {
            pacc.x += v.x; pacc.y += v.y; pacc.z += v.z; pacc.w += v.w;
        } else {
            int b = batch_id[row];
            atomicAdd(&pooled[b * 64 + c4 + 0], v.x);
            atomicAdd(&pooled[b * 64 + c4 + 1], v.y);
            atomicAdd(&pooled[b * 64 + c4 + 2], v.z);
            atomicAdd(&pooled[b * 64 + c4 + 3], v.w);
        }
    }
    if (fast) {
        pacc.x += __shfl_xor(pacc.x, 16); pacc.x += __shfl_xor(pacc.x, 32);
        pacc.y += __shfl_xor(pacc.y, 16); pacc.y += __shfl_xor(pacc.y, 32);
        pacc.z += __shfl_xor(pacc.z, 16); pacc.z += __shfl_xor(pacc.z, 32);
        pacc.w += __shfl_xor(pacc.w, 16); pacc.w += __shfl_xor(pacc.w, 32);
        if ((lane >> 4) == 0) {
            int b = batch_id[wr0];
            atomicAdd(&pooled[b * 64 + c4 + 0], pacc.x);
            atomicAdd(&pooled[b * 64 + c4 + 1], pacc.y);
            atomicAdd(&pooled[b * 64 + c4 + 2], pacc.z);
            atomicAdd(&pooled[b * 64 + c4 + 3], pacc.w);
        }
    }
}

// Phase A of the layer: gather FEATURE-HALF 0 only.
// agg0[node][0:32] = (1+eps)*h[node][0:32] + sum rbuf_h0[src][0:32].
// The half0 table is one contiguous 3.2MB block -> fits a 4MB per-XCD L2,
// removing the ~37% capacity-miss rate measured on the fused 6.4MB table
// (R8: FETCH 65.6MB vs ~38MB compulsory). 8 lanes/row, uint2 (8B) each.
__global__ __launch_bounds__(512) void k_gath(
    const float* __restrict__ h_in, const float* __restrict__ eps, int l,
    const int* __restrict__ cnt, const unsigned short* __restrict__ csr_src,
    const unsigned short* __restrict__ rbuf_in, float* __restrict__ agg0) {
    int tid = threadIdx.x;
    int lane = tid & 63, wave = tid >> 6;
    int g = lane >> 3, f = lane & 7;
    int row = blockIdx.x * 64 + wave * 8 + g;
    if (row >= N_NODES) return;
    float e1 = 1.0f + eps[l];
    const uint2* tab = (const uint2*)rbuf_in;   // half0 table
    float a0 = 0.f, a1 = 0.f, a2 = 0.f, a3 = 0.f;
    int deg = cnt[row]; if (deg > CAP) deg = CAP;
    const unsigned short* rowp = csr_src + (size_t)row * CAP;
    int e = 0;
    for (; e + 3 < deg; e += 4) {
        ushort4 s4 = *(const ushort4*)(rowp + e);   // group-uniform 8B
        uint2 u0 = tab[(size_t)s4.x * 8 + f];
        uint2 u1 = tab[(size_t)s4.y * 8 + f];
        uint2 u2 = tab[(size_t)s4.z * 8 + f];
        uint2 u3 = tab[(size_t)s4.w * 8 + f];
        a0 += bflo(u0.x); a1 += bfhi(u0.x); a2 += bflo(u0.y); a3 += bfhi(u0.y);
        a0 += bflo(u1.x); a1 += bfhi(u1.x); a2 += bflo(u1.y); a3 += bfhi(u1.y);
        a0 += bflo(u2.x); a1 += bfhi(u2.x); a2 += bflo(u2.y); a3 += bfhi(u2.y);
        a0 += bflo(u3.x); a1 += bfhi(u3.x); a2 += bflo(u3.y); a3 += bfhi(u3.y);
    }
    for (; e < deg; ++e) {
        uint2 u = tab[(size_t)rowp[e] * 8 + f];
        a0 += bflo(u.x); a1 += bfhi(u.x); a2 += bflo(u.y); a3 += bfhi(u.y);
    }
    // lane f owns feats [4f, 4f+4) of half0
    float4 hv = *(const float4*)(h_in + (size_t)row * 64 + 4 * f);
    float4 o;
    o.x = e1 * hv.x + a0; o.y = e1 * hv.y + a1;
    o.z = e1 * hv.z + a2; o.w = e1 * hv.w + a3;
    *(float4*)(agg0 + (size_t)row * 32 + 4 * f) = o;
}

// Phase B: load agg0 (half0, streamed) + gather half1 (its own 3.2MB
// L2-resident table) + dual GEMM + epilogue. 512 threads (8 waves).
// rbuf double-buffered across layers (read l, write l+1).
__global__ __launch_bounds__(512) void k_gin(
    const float* __restrict__ h_in, const float* __restrict__ eps, int l,
    const int* __restrict__ cnt, const unsigned short* __restrict__ csr_src,
    const unsigned short* __restrict__ rbuf_in, const float* __restrict__ agg0,
    const float* __restrict__ W1, const float* __restrict__ b1,
    const float* __restrict__ g1, const float* __restrict__ be1,
    const float* __restrict__ m1, const float* __restrict__ v1,
    const float* __restrict__ W2, const float* __restrict__ b2,
    const float* __restrict__ g2, const float* __restrict__ be2,
    const float* __restrict__ m2, const float* __restrict__ v2,
    const float* __restrict__ vn, const int* __restrict__ batch_id,
    float* __restrict__ h, float* __restrict__ out,
    unsigned short* __restrict__ rbuf_out, float* __restrict__ pooled,
    int last) {
    __shared__ float sW[64 * 64];
    __shared__ float sIn[64 * 68];
    int tid = threadIdx.x;
    int row0 = blockIdx.x * 64;
    int lane = tid & 63;
    int wave = tid >> 6;

#pragma unroll
    for (int i = 0; i < 2; ++i)
        ((float4*)sW)[tid + 512 * i] = ((const float4*)W1)[tid + 512 * i];

    // ---- half0 from agg0: cooperative stream (512 float4) ----
    {
        int r = tid >> 3, j = tid & 7;
        int row = row0 + r;
        float4 val = make_float4(0.f, 0.f, 0.f, 0.f);
        if (row < N_NODES) val = *(const float4*)(agg0 + (size_t)row * 32 + j * 4);
        *(float4*)(sIn + r * 68 + j * 4) = val;
    }

    // ---- half1 gather: 8 lanes/row, uint2 each; table = 3.2MB block ----
    {
        int g = lane >> 3, f = lane & 7;
        int row = row0 + wave * 8 + g;
        float e1 = 1.0f + eps[l];
        const uint2* tab = (const uint2*)(rbuf_in + (size_t)N_NODES * 32); // half1
        float a0 = 0.f, a1 = 0.f, a2 = 0.f, a3 = 0.f;
        if (row < N_NODES) {
            int deg = cnt[row]; if (deg > CAP) deg = CAP;
            const unsigned short* rowp = csr_src + (size_t)row * CAP;
            int e = 0;
            for (; e + 3 < deg; e += 4) {
                ushort4 s4 = *(const ushort4*)(rowp + e);
                uint2 u0 = tab[(size_t)s4.x * 8 + f];
                uint2 u1 = tab[(size_t)s4.y * 8 + f];
                uint2 u2 = tab[(size_t)s4.z * 8 + f];
                uint2 u3 = tab[(size_t)s4.w * 8 + f];
                a0 += bflo(u0.x); a1 += bfhi(u0.x); a2 += bflo(u0.y); a3 += bfhi(u0.y);
                a0 += bflo(u1.x); a1 += bfhi(u1.x); a2 += bflo(u1.y); a3 += bfhi(u1.y);
                a0 += bflo(u2.x); a1 += bfhi(u2.x); a2 += bflo(u2.y); a3 += bfhi(u2.y);
                a0 += bflo(u3.x); a1 += bfhi(u3.x); a2 += bflo(u3.y); a3 += bfhi(u3.y);
            }
            for (; e < deg; ++e) {
                uint2 u = tab[(size_t)rowp[e] * 8 + f];
                a0 += bflo(u.x); a1 += bfhi(u.x); a2 += bflo(u.y); a3 += bfhi(u.y);
            }
        }
        float* sp = sIn + (wave * 8 + g) * 68 + 32 + 4 * f;
        if (row < N_NODES) {
            float4 hv = *(const float4*)(h_in + (size_t)row * 64 + 32 + 4 * f);
            float4 o;
            o.x = e1 * hv.x + a0; o.y = e1 * hv.y + a1;
            o.z = e1 * hv.z + a2; o.w = e1 * hv.w + a3;
            *(float4*)sp = o;
        } else {
            *(float4*)sp = make_float4(0.f, 0.f, 0.f, 0.f);
        }
    }
    __syncthreads();

    // ---- GEMM1: 2 rows/thread ----
    int c4 = (tid & 15) * 4;
    int rg = tid >> 4;          // 0..31 -> rows 2rg, 2rg+1
    float acc[2][4] = {{0.f}};
#pragma unroll 8
    for (int k = 0; k < 64; ++k) {
        float4 wv = *(const float4*)(sW + k * 64 + c4);
        float a0 = sIn[(2 * rg + 0) * 68 + k];
        float a1 = sIn[(2 * rg + 1) * 68 + k];
        acc[0][0] += a0 * wv.x; acc[0][1] += a0 * wv.y; acc[0][2] += a0 * wv.z; acc[0][3] += a0 * wv.w;
        acc[1][0] += a1 * wv.x; acc[1][1] += a1 * wv.y; acc[1][2] += a1 * wv.z; acc[1][3] += a1 * wv.w;
    }
    float scl[4], shf[4];
#pragma unroll
    for (int j = 0; j < 4; ++j) {
        int c = c4 + j;
        float sc = g1[c] * rsqrtf(v1[c] + 1e-5f);
        scl[j] = sc;
        shf[j] = be1[c] - m1[c] * sc + b1[c] * sc;
    }
    __syncthreads();   // all GEMM1 sIn/sW reads complete
#pragma unroll
    for (int i = 0; i < 2; ++i) {
        float4 z;
        z.x = fmaxf(acc[i][0] * scl[0] + shf[0], 0.f);
        z.y = fmaxf(acc[i][1] * scl[1] + shf[1], 0.f);
        z.z = fmaxf(acc[i][2] * scl[2] + shf[2], 0.f);
        z.w = fmaxf(acc[i][3] * scl[3] + shf[3], 0.f);
        *(float4*)(sIn + (2 * rg + i) * 68 + c4) = z;
    }
#pragma unroll
    for (int i = 0; i < 2; ++i)
        ((float4*)sW)[tid + 512 * i] = ((const float4*)W2)[tid + 512 * i];
    __syncthreads();

    // ---- GEMM2 ----
    float acc2[2][4] = {{0.f}};
#pragma unroll 8
    for (int k = 0; k < 64; ++k) {
        float4 wv = *(const float4*)(sW + k * 64 + c4);
        float a0 = sIn[(2 * rg + 0) * 68 + k];
        float a1 = sIn[(2 * rg + 1) * 68 + k];
        acc2[0][0] += a0 * wv.x; acc2[0][1] += a0 * wv.y; acc2[0][2] += a0 * wv.z; acc2[0][3] += a0 * wv.w;
        acc2[1][0] += a1 * wv.x; acc2[1][1] += a1 * wv.y; acc2[1][2] += a1 * wv.z; acc2[1][3] += a1 * wv.w;
    }
#pragma unroll
    for (int j = 0; j < 4; ++j) {
        int c = c4 + j;
        float sc = g2[c] * rsqrtf(v2[c] + 1e-5f);
        scl[j] = sc;
        shf[j] = be2[c] - m2[c] * sc + b2[c] * sc;
    }

    int wr0 = row0 + wave * 8;
    bool full = (wr0 + 7 < N_NODES);
    bool fast = (!last) && full && (batch_id[wr0] == batch_id[wr0 + 7]);
    float4 pacc = make_float4(0.f, 0.f, 0.f, 0.f);
#pragma unroll
    for (int r = 0; r < 2; ++r) {
        int row = row0 + rg * 2 + r;
        if (row >= N_NODES) continue;
        int b = batch_id[row];
        float4 vv = *(const float4*)(vn + b * 64 + c4);
        float4 v;
        v.x = fmaxf(acc2[r][0] * scl[0] + shf[0], 0.f) + vv.x;
        v.y = fmaxf(acc2[r][1] * scl[1] + shf[1], 0.f) + vv.y;
        v.z = fmaxf(acc2[r][2] * scl[2] + shf[2], 0.f) + vv.z;
        v.w = fmaxf(acc2[r][3] * scl[3] + shf[3], 0.f) + vv.w;
        float4 o = *(const float4*)(out + (size_t)row * 64 + c4);
        o.x += v.x; o.y += v.y; o.z += v.z; o.w += v.w;
        *(float4*)(out + (size_t)row * 64 + c4) = o;
        if (!last) {
            *(float4*)(h + (size_t)row * 64 + c4) = v;
            ushort4 rb;
            rb.x = f2bf(fmaxf(v.x, 0.f)); rb.y = f2bf(fmaxf(v.y, 0.f));
            rb.z = f2bf(fmaxf(v.z, 0.f)); rb.w = f2bf(fmaxf(v.w, 0.f));
            *(ushort4*)(rbuf_out + (size_t)(c4 >> 5) * ((size_t)N_NODES * 32)
                        + (size_t)row * 32 + (c4 & 31)) = rb;
            if (fast) {
                pacc.x += v.x; pacc.y += v.y; pacc.z += v.z; pacc.w += v.w;
            } else {
                atomicAdd(&pooled[b * 64 + c4 + 0], v.x);
                atomicAdd(&pooled[b * 64 + c4 + 1], v.y);
                atomicAdd(&pooled[b * 64 + c4 + 2], v.z);
                atomicAdd(&pooled[b * 64 + c4 + 3], v.w);
            }
        }
    }
    if (fast) {
        pacc.x += __shfl_xor(pacc.x, 16); pacc.x += __shfl_xor(pacc.x, 32);
        pacc.y += __shfl_xor(pacc.y, 16); pacc.y += __shfl_xor(pacc.y, 32);
        pacc.z += __shfl_xor(pacc.z, 16); pacc.z += __shfl_xor(pacc.z, 32);
        pacc.w += __shfl_xor(pacc.w, 16); pacc.w += __shfl_xor(pacc.w, 32);
        if ((lane >> 4) == 0) {
            int b = batch_id[wr0];
            atomicAdd(&pooled[b * 64 + c4 + 0], pacc.x);
            atomicAdd(&pooled[b * 64 + c4 + 1], pacc.y);
            atomicAdd(&pooled[b * 64 + c4 + 2], pacc.z);
            atomicAdd(&pooled[b * 64 + c4 + 3], pacc.w);
        }
    }
}

// Fused vn MLP, 1024 threads (2 rows/thread), separate kernel.
__global__ __launch_bounds__(1024) void k_vnmlp(
    const float* __restrict__ pooled_in,
    const float* __restrict__ W1, const float* __restrict__ b1,
    const float* __restrict__ g1, const float* __restrict__ be1,
    const float* __restrict__ m1, const float* __restrict__ v1,
    const float* __restrict__ W2, const float* __restrict__ b2,
    const float* __restrict__ g2, const float* __restrict__ be2,
    const float* __restrict__ m2, const float* __restrict__ v2,
    float* __restrict__ vn_out, float* __restrict__ pooled_out) {
    __shared__ float sP[128 * 68];
    __shared__ float sW[64 * 64];
    int tid = threadIdx.x;

    ((float4*)sW)[tid] = ((const float4*)W1)[tid];          // 1024 float4 exactly
#pragma unroll
    for (int i = 0; i < 2; ++i) {
        int idx = tid + 1024 * i;
        int r = idx >> 4, j = idx & 15;
        ((float4*)(sP + r * 68))[j] = ((const float4*)pooled_in)[idx];
    }
    __syncthreads();

    int c4 = (tid & 15) * 4, rg = tid >> 4;   // rg: 0..63 -> rows 2rg, 2rg+1
    float acc[2][4] = {{0.f}};
#pragma unroll 8
    for (int k = 0; k < 64; ++k) {
        float4 w = *(const float4*)(sW + k * 64 + c4);
#pragma unroll
        for (int i = 0; i < 2; ++i) {
            float a = sP[(rg * 2 + i) * 68 + k];
            acc[i][0] += a * w.x; acc[i][1] += a * w.y;
            acc[i][2] += a * w.z; acc[i][3] += a * w.w;
        }
    }
    float scl[4], shf[4];
#pragma unroll
    for (int j = 0; j < 4; ++j) {
        int c = c4 + j;
        float sc = g1[c] * rsqrtf(v1[c] + 1e-5f);
        scl[j] = sc;
        shf[j] = be1[c] - m1[c] * sc + b1[c] * sc;
    }
    __syncthreads();
#pragma unroll
    for (int i = 0; i < 2; ++i) {
        float4 z;
        z.x = fmaxf(acc[i][0] * scl[0] + shf[0], 0.f);
        z.y = fmaxf(acc[i][1] * scl[1] + shf[1], 0.f);
        z.z = fmaxf(acc[i][2] * scl[2] + shf[2], 0.f);
        z.w = fmaxf(acc[i][3] * scl[3] + shf[3], 0.f);
        *(float4*)(sP + (rg * 2 + i) * 68 + c4) = z;
    }
    ((float4*)sW)[tid] = ((const float4*)W2)[tid];
    __syncthreads();

    float acc2[2][4] = {{0.f}};
#pragma unroll 8
    for (int k = 0; k < 64; ++k) {
        float4 w = *(const float4*)(sW + k * 64 + c4);
#pragma unroll
        for (int i = 0; i < 2; ++i) {
            float a = sP[(rg * 2 + i) * 68 + k];
            acc2[i][0] += a * w.x; acc2[i][1] += a * w.y;
            acc2[i][2] += a * w.z; acc2[i][3] += a * w.w;
        }
    }
#pragma unroll
    for (int j = 0; j < 4; ++j) {
        int c = c4 + j;
        float sc = g2[c] * rsqrtf(v2[c] + 1e-5f);
        scl[j] = sc;
        shf[j] = be2[c] - m2[c] * sc + b2[c] * sc;
    }
#pragma unroll
    for (int i = 0; i < 2; ++i) {
        int row = rg * 2 + i;
        float4 o;
        o.x = fmaxf(acc2[i][0] * scl[0] + shf[0], 0.f);
        o.y = fmaxf(acc2[i][1] * scl[1] + shf[1], 0.f);
        o.z = fmaxf(acc2[i][2] * scl[2] + shf[2], 0.f);
        o.w = fmaxf(acc2[i][3] * scl[3] + shf[3], 0.f);
        *(float4*)(vn_out + row * 64 + c4) = o;
        *(float4*)(pooled_out + row * 64 + c4) = o;
    }
}

extern "C" void kernel_launch(void* const* d_in, const int* in_sizes, int n_in,
                              void* d_out, int out_size, void* d_ws, size_t ws_size,
                              hipStream_t stream) {
    const float* x      = (const float*)d_in[0];
    const float* lin_W  = (const float*)d_in[1];
    const float* lin_b  = (const float*)d_in[2];
    const float* eps    = (const float*)d_in[3];
    const float* gin_W1 = (const float*)d_in[4];
    const float* gin_b1 = (const float*)d_in[5];
    const float* gbn_g  = (const float*)d_in[6];
    const float* gbn_b  = (const float*)d_in[7];
    const float* gbn_m  = (const float*)d_in[8];
    const float* gbn_v  = (const float*)d_in[9];
    const float* gin_W2 = (const float*)d_in[10];
    const float* gin_b2 = (const float*)d_in[11];
    const float* bn_g   = (const float*)d_in[12];
    const float* bn_b   = (const float*)d_in[13];
    const float* bn_m   = (const float*)d_in[14];
    const float* bn_v   = (const float*)d_in[15];
    const float* vn_emb = (const float*)d_in[16];
    const float* vn_W1  = (const float*)d_in[17];
    const float* vn_b1  = (const float*)d_in[18];
    const float* v1g    = (const float*)d_in[19];
    const float* v1b    = (const float*)d_in[20];
    const float* v1m    = (const float*)d_in[21];
    const float* v1v    = (const float*)d_in[22];
    const float* vn_W2  = (const float*)d_in[23];
    const float* vn_b2  = (const float*)d_in[24];
    const float* v2g    = (const float*)d_in[25];
    const float* v2b    = (const float*)d_in[26];
    const float* v2m    = (const float*)d_in[27];
    const float* v2v    = (const float*)d_in[28];
    const int* src      = (const int*)d_in[29];
    const int* dst      = (const int*)d_in[30];
    const int* batch_id = (const int*)d_in[31];
    float* out = (float*)d_out;

    // workspace layout (~40.4 MB)
    float* h      = (float*)d_ws;                      // N*64 f32
    unsigned short* rbufA = (unsigned short*)(h + (size_t)N_NODES * 64); // 2 x N*32 bf16 half-tables
    unsigned short* rbufB = rbufA + (size_t)N_NODES * 64;                // 2 x N*32 bf16 half-tables
    float* agg0   = (float*)(rbufB + (size_t)N_NODES * 64);              // N*32 f32
    float* vn     = agg0 + (size_t)N_NODES * 32;       // B*64
    float* pooled = vn  + (size_t)NB * 64;             // B*64
    int*   cnt    = (int*)(pooled + (size_t)NB * 64);  // N
    unsigned short* csr_src = (unsigned short*)(cnt + N_NODES); // N*CAP ushort (8 MB)

    // ---- Bucket-CSR build: 8 sub-passes + pooled init tail ----
    hipMemsetAsync(cnt, 0, N_NODES * sizeof(int), stream);
    k_build<<<EDGE_BLOCKS * 8 + INIT_BLOCKS, 256, 0, stream>>>(src, dst, cnt, csr_src,
                                                               vn_emb, pooled);

    // input linear fused with layer-0 pre
    k_lin_pre<<<GB, 256, 0, stream>>>(x, lin_W, lin_b, vn_emb, batch_id,
                                      h, out, rbufA, pooled);

    for (int l = 0; l < 4; ++l) {
        unsigned short* rin  = (l & 1) ? rbufB : rbufA;
        unsigned short* rout = (l & 1) ? rbufA : rbufB;
        // vn MLP first: pooled(l) -> vn(l+1), pooled(l+1)-init
        k_vnmlp<<<1, 1024, 0, stream>>>(pooled,
                                        vn_W1 + l * 4096, vn_b1 + l * 64,
                                        v1g + l * 64, v1b + l * 64, v1m + l * 64, v1v + l * 64,
                                        vn_W2 + l * 4096, vn_b2 + l * 64,
                                        v2g + l * 64, v2b + l * 64, v2m + l * 64, v2v + l * 64,
                                        vn, pooled);
        // phase A: half0 gather (3.2MB table, L2-resident)
        k_gath<<<GB, 512, 0, stream>>>(h, eps, l, cnt, csr_src, rin, agg0);
        // phase B: half1 gather + GEMMs + epilogue
        k_gin<<<GB, 512, 0, stream>>>(h, eps, l, cnt, csr_src, rin, agg0,
                                      gin_W1 + l * 4096, gin_b1 + l * 64,
                                      gbn_g + l * 64, gbn_b + l * 64,
                                      gbn_m + l * 64, gbn_v + l * 64,
                                      gin_W2 + l * 4096, gin_b2 + l * 64,
                                      bn_g + l * 64, bn_b + l * 64,
                                      bn_m + l * 64, bn_v + l * 64,
                                      vn, batch_id, h, out, rout, pooled,
                                      l == 3);
    }
}

// Round 12
// 469.212 us; speedup vs baseline: 1.1761x; 1.1761x over previous
//
#include <hip/hip_runtime.h>

#define N_NODES 50000
#define N_EDGES 1600000
#define NB 128
#define GB 782          // ceil(N/64)
#define CAP 80                   // bucket slots per node; P(deg>80)~1e-17 (Poisson 32)
#define NODE_RANGE 6250          // N/8: dst-range per build sub-pass
#define EDGE_BLOCKS 6250         // N_EDGES/256
#define INIT_BLOCKS 32           // pooled init (NB*64 floats)

__device__ __forceinline__ unsigned short f2bf(float f) {
    unsigned u = __float_as_uint(f);
    unsigned r = (u + 0x7FFFu + ((u >> 16) & 1u)) >> 16;   // RNE
    return (unsigned short)r;
}
__device__ __forceinline__ float bflo(unsigned u) { return __uint_as_float(u << 16); }
__device__ __forceinline__ float bfhi(unsigned u) { return __uint_as_float(u & 0xFFFF0000u); }

// ---- Bucket-CSR build: 8 dst-range sub-passes (bid&7). ----
// Measured best (74us). bid&7->XCD round-robin pins each range's cnt/csr
// lines to one XCD L2; single-pass was 137us (store scatter too wide),
// NT variants worse (R1/R10: NT bypasses L2 write-combining on gfx950).
__global__ __launch_bounds__(256) void k_build(
    const int* __restrict__ src, const int* __restrict__ dst,
    int* __restrict__ cnt, unsigned short* __restrict__ csr_src,
    const float* __restrict__ vn_emb, float* __restrict__ pooled) {
    int bid = blockIdx.x;
    if (bid >= EDGE_BLOCKS * 8) {
        int t = (bid - EDGE_BLOCKS * 8) * 256 + threadIdx.x;
        pooled[t] = vn_emb[t & 63];
        return;
    }
    int range = bid & 7;
    int e = (bid >> 3) * 256 + threadIdx.x;
    int d = dst[e];
    if (d / NODE_RANGE != range) return;
    int pos = atomicAdd(&cnt[d], 1);
    if (pos < CAP) csr_src[(size_t)d * CAP + pos] = (unsigned short)src[e];
}

// Input linear fused with layer-0 "pre": h = x@W + b + vn_emb; out = h;
// rbuf = bf16(relu(h)) node-major; pooled += segsum(h)
__global__ __launch_bounds__(256) void k_lin_pre(
    const float* __restrict__ in, const float* __restrict__ W,
    const float* __restrict__ bias, const float* __restrict__ vn_emb,
    const int* __restrict__ batch_id,
    float* __restrict__ h, float* __restrict__ out,
    unsigned short* __restrict__ rbuf, float* __restrict__ pooled) {
    __shared__ float sW[64 * 64];
    __shared__ float sIn[64 * 68];
    int tid = threadIdx.x;
    int row0 = blockIdx.x * 64;

    const float4* W4 = (const float4*)W;
#pragma unroll
    for (int i = 0; i < 4; ++i) ((float4*)sW)[tid + 256 * i] = W4[tid + 256 * i];
    const float4* in4 = (const float4*)in;
#pragma unroll
    for (int i = 0; i < 4; ++i) {
        int idx = tid + 256 * i;
        int r = idx >> 4, j = idx & 15;
        float4 val = make_float4(0.f, 0.f, 0.f, 0.f);
        if (row0 + r < N_NODES) val = in4[(size_t)(row0 + r) * 16 + j];
        ((float4*)(sIn + r * 68))[j] = val;
    }
    __syncthreads();

    int c4 = (tid & 15) * 4;
    int rl = (tid >> 4) * 4;
    float acc[4][4] = {{0.f}};
#pragma unroll 8
    for (int k = 0; k < 64; ++k) {
        float4 wv = *(const float4*)(sW + k * 64 + c4);
        float a0 = sIn[(rl + 0) * 68 + k];
        float a1 = sIn[(rl + 1) * 68 + k];
        float a2 = sIn[(rl + 2) * 68 + k];
        float a3 = sIn[(rl + 3) * 68 + k];
        acc[0][0] += a0 * wv.x; acc[0][1] += a0 * wv.y; acc[0][2] += a0 * wv.z; acc[0][3] += a0 * wv.w;
        acc[1][0] += a1 * wv.x; acc[1][1] += a1 * wv.y; acc[1][2] += a1 * wv.z; acc[1][3] += a1 * wv.w;
        acc[2][0] += a2 * wv.x; acc[2][1] += a2 * wv.y; acc[2][2] += a2 * wv.z; acc[2][3] += a2 * wv.w;
        acc[3][0] += a3 * wv.x; acc[3][1] += a3 * wv.y; acc[3][2] += a3 * wv.z; acc[3][3] += a3 * wv.w;
    }
    float shf[4];
#pragma unroll
    for (int j = 0; j < 4; ++j) shf[j] = bias[c4 + j] + vn_emb[c4 + j];

    int lane = tid & 63;
    int wave = tid >> 6;
    int wr0 = row0 + wave * 16;
    bool full = (wr0 + 15 < N_NODES);
    bool fast = full && (batch_id[wr0] == batch_id[wr0 + 15]);
    float4 pacc = make_float4(0.f, 0.f, 0.f, 0.f);
#pragma unroll
    for (int r = 0; r < 4; ++r) {
        int row = row0 + rl + r;
        if (row >= N_NODES) continue;
        float4 v;
        v.x = acc[r][0] + shf[0];
        v.y = acc[r][1] + shf[1];
        v.z = acc[r][2] + shf[2];
        v.w = acc[r][3] + shf[3];
        *(float4*)(h + (size_t)row * 64 + c4) = v;
        *(float4*)(out + (size_t)row * 64 + c4) = v;
        ushort4 rb;
        rb.x = f2bf(fmaxf(v.x, 0.f)); rb.y = f2bf(fmaxf(v.y, 0.f));
        rb.z = f2bf(fmaxf(v.z, 0.f)); rb.w = f2bf(fmaxf(v.w, 0.f));
        *(ushort4*)(rbuf + (size_t)row * 64 + c4) = rb;
        if (fast) {
            pacc.x += v.x; pacc.y += v.y; pacc.z += v.z; pacc.w += v.w;
        } else {
            int b = batch_id[row];
            atomicAdd(&pooled[b * 64 + c4 + 0], v.x);
            atomicAdd(&pooled[b * 64 + c4 + 1], v.y);
            atomicAdd(&pooled[b * 64 + c4 + 2], v.z);
            atomicAdd(&pooled[b * 64 + c4 + 3], v.w);
        }
    }
    if (fast) {
        pacc.x += __shfl_xor(pacc.x, 16); pacc.x += __shfl_xor(pacc.x, 32);
        pacc.y += __shfl_xor(pacc.y, 16); pacc.y += __shfl_xor(pacc.y, 32);
        pacc.z += __shfl_xor(pacc.z, 16); pacc.z += __shfl_xor(pacc.z, 32);
        pacc.w += __shfl_xor(pacc.w, 16); pacc.w += __shfl_xor(pacc.w, 32);
        if ((lane >> 4) == 0) {
            int b = batch_id[wr0];
            atomicAdd(&pooled[b * 64 + c4 + 0], pacc.x);
            atomicAdd(&pooled[b * 64 + c4 + 1], pacc.y);
            atomicAdd(&pooled[b * 64 + c4 + 2], pacc.z);
            atomicAdd(&pooled[b * 64 + c4 + 3], pacc.w);
        }
    }
}

// Fused GIN layer with in-kernel aggregation (R8 structure, 485us total).
// 512 threads (8 waves); shuffle-free gather, 8 lanes/row, lane f4 owns
// feats [8f4,8f4+8). GATHER UNROLL 8: one 16B group-uniform edge-index
// load feeds 8 INDEPENDENT uint4 gathers -> 2x outstanding loads per
// stall window (kernel is gather-miss-latency-bound; ~6x above its
// arithmetic floor). Keep VGPR <= 64 (32 waves/CU).
__global__ __launch_bounds__(512) void k_gin(
    const float* __restrict__ h_in, const float* __restrict__ eps, int l,
    const int* __restrict__ cnt, const unsigned short* __restrict__ csr_src,
    const unsigned short* __restrict__ rbuf_in,
    const float* __restrict__ W1, const float* __restrict__ b1,
    const float* __restrict__ g1, const float* __restrict__ be1,
    const float* __restrict__ m1, const float* __restrict__ v1,
    const float* __restrict__ W2, const float* __restrict__ b2,
    const float* __restrict__ g2, const float* __restrict__ be2,
    const float* __restrict__ m2, const float* __restrict__ v2,
    const float* __restrict__ vn, const int* __restrict__ batch_id,
    float* __restrict__ h, float* __restrict__ out,
    unsigned short* __restrict__ rbuf_out, float* __restrict__ pooled,
    int last) {
    __shared__ float sW[64 * 64];
    __shared__ float sIn[64 * 68];
    int tid = threadIdx.x;
    int row0 = blockIdx.x * 64;
    int lane = tid & 63;
    int wave = tid >> 6;

#pragma unroll
    for (int i = 0; i < 2; ++i)
        ((float4*)sW)[tid + 512 * i] = ((const float4*)W1)[tid + 512 * i];

    // ---- gather: wave w owns rows [row0+8w, +8); 8 lanes/row ----
    {
        int g = lane >> 3, f4 = lane & 7;
        int row = row0 + wave * 8 + g;
        float e1 = 1.0f + eps[l];
        const uint4* tab4 = (const uint4*)rbuf_in;
        float aL0 = 0.f, aH0 = 0.f, aL1 = 0.f, aH1 = 0.f;
        float aL2 = 0.f, aH2 = 0.f, aL3 = 0.f, aH3 = 0.f;
        if (row < N_NODES) {
            int deg = cnt[row]; if (deg > CAP) deg = CAP;
            const unsigned short* rowp = csr_src + (size_t)row * CAP;
            int e = 0;
            for (; e + 7 < deg; e += 8) {
                ushort4 sa = *(const ushort4*)(rowp + e);       // uniform 8B
                ushort4 sb = *(const ushort4*)(rowp + e + 4);   // uniform 8B
                uint4 u0 = tab4[(size_t)sa.x * 8 + f4];
                uint4 u1 = tab4[(size_t)sa.y * 8 + f4];
                uint4 u2 = tab4[(size_t)sa.z * 8 + f4];
                uint4 u3 = tab4[(size_t)sa.w * 8 + f4];
                uint4 u4 = tab4[(size_t)sb.x * 8 + f4];
                uint4 u5 = tab4[(size_t)sb.y * 8 + f4];
                uint4 u6 = tab4[(size_t)sb.z * 8 + f4];
                uint4 u7 = tab4[(size_t)sb.w * 8 + f4];
                aL0 += bflo(u0.x); aH0 += bfhi(u0.x); aL1 += bflo(u0.y); aH1 += bfhi(u0.y);
                aL2 += bflo(u0.z); aH2 += bfhi(u0.z); aL3 += bflo(u0.w); aH3 += bfhi(u0.w);
                aL0 += bflo(u1.x); aH0 += bfhi(u1.x); aL1 += bflo(u1.y); aH1 += bfhi(u1.y);
                aL2 += bflo(u1.z); aH2 += bfhi(u1.z); aL3 += bflo(u1.w); aH3 += bfhi(u1.w);
                aL0 += bflo(u2.x); aH0 += bfhi(u2.x); aL1 += bflo(u2.y); aH1 += bfhi(u2.y);
                aL2 += bflo(u2.z); aH2 += bfhi(u2.z); aL3 += bflo(u2.w); aH3 += bfhi(u2.w);
                aL0 += bflo(u3.x); aH0 += bfhi(u3.x); aL1 += bflo(u3.y); aH1 += bfhi(u3.y);
                aL2 += bflo(u3.z); aH2 += bfhi(u3.z); aL3 += bflo(u3.w); aH3 += bfhi(u3.w);
                aL0 += bflo(u4.x); aH0 += bfhi(u4.x); aL1 += bflo(u4.y); aH1 += bfhi(u4.y);
                aL2 += bflo(u4.z); aH2 += bfhi(u4.z); aL3 += bflo(u4.w); aH3 += bfhi(u4.w);
                aL0 += bflo(u5.x); aH0 += bfhi(u5.x); aL1 += bflo(u5.y); aH1 += bfhi(u5.y);
                aL2 += bflo(u5.z); aH2 += bfhi(u5.z); aL3 += bflo(u5.w); aH3 += bfhi(u5.w);
                aL0 += bflo(u6.x); aH0 += bfhi(u6.x); aL1 += bflo(u6.y); aH1 += bfhi(u6.y);
                aL2 += bflo(u6.z); aH2 += bfhi(u6.z); aL3 += bflo(u6.w); aH3 += bfhi(u6.w);
                aL0 += bflo(u7.x); aH0 += bfhi(u7.x); aL1 += bflo(u7.y); aH1 += bfhi(u7.y);
                aL2 += bflo(u7.z); aH2 += bfhi(u7.z); aL3 += bflo(u7.w); aH3 += bfhi(u7.w);
            }
            for (; e + 3 < deg; e += 4) {
                ushort4 sa = *(const ushort4*)(rowp + e);
                uint4 u0 = tab4[(size_t)sa.x * 8 + f4];
                uint4 u1 = tab4[(size_t)sa.y * 8 + f4];
                uint4 u2 = tab4[(size_t)sa.z * 8 + f4];
                uint4 u3 = tab4[(size_t)sa.w * 8 + f4];
                aL0 += bflo(u0.x); aH0 += bfhi(u0.x); aL1 += bflo(u0.y); aH1 += bfhi(u0.y);
                aL2 += bflo(u0.z); aH2 += bfhi(u0.z); aL3 += bflo(u0.w); aH3 += bfhi(u0.w);
                aL0 += bflo(u1.x); aH0 += bfhi(u1.x); aL1 += bflo(u1.y); aH1 += bfhi(u1.y);
                aL2 += bflo(u1.z); aH2 += bfhi(u1.z); aL3 += bflo(u1.w); aH3 += bfhi(u1.w);
                aL0 += bflo(u2.x); aH0 += bfhi(u2.x); aL1 += bflo(u2.y); aH1 += bfhi(u2.y);
                aL2 += bflo(u2.z); aH2 += bfhi(u2.z); aL3 += bflo(u2.w); aH3 += bfhi(u2.w);
                aL0 += bflo(u3.x); aH0 += bfhi(u3.x); aL1 += bflo(u3.y); aH1 += bfhi(u3.y);
                aL2 += bflo(u3.z); aH2 += bfhi(u3.z); aL3 += bflo(u3.w); aH3 += bfhi(u3.w);
            }
            for (; e < deg; ++e) {
                uint4 u = tab4[(size_t)rowp[e] * 8 + f4];
                aL0 += bflo(u.x); aH0 += bfhi(u.x); aL1 += bflo(u.y); aH1 += bfhi(u.y);
                aL2 += bflo(u.z); aH2 += bfhi(u.z); aL3 += bflo(u.w); aH3 += bfhi(u.w);
            }
        }
        float* sp = sIn + (wave * 8 + g) * 68 + f4 * 8;
        if (row < N_NODES) {
            const float* hp = h_in + (size_t)row * 64 + f4 * 8;
            float4 h0 = *(const float4*)hp;
            float4 h1 = *(const float4*)(hp + 4);
            float4 o0, o1;
            o0.x = e1 * h0.x + aL0; o0.y = e1 * h0.y + aH0;
            o0.z = e1 * h0.z + aL1; o0.w = e1 * h0.w + aH1;
            o1.x = e1 * h1.x + aL2; o1.y = e1 * h1.y + aH2;
            o1.z = e1 * h1.z + aL3; o1.w = e1 * h1.w + aH3;
            *(float4*)sp = o0;
            *(float4*)(sp + 4) = o1;
        } else {
            *(float4*)sp = make_float4(0.f, 0.f, 0.f, 0.f);
            *(float4*)(sp + 4) = make_float4(0.f, 0.f, 0.f, 0.f);
        }
    }
    __syncthreads();

    // ---- GEMM1: 2 rows/thread ----
    int c4 = (tid & 15) * 4;
    int rg = tid >> 4;          // 0..31 -> rows 2rg, 2rg+1
    float acc[2][4] = {{0.f}};
#pragma unroll 8
    for (int k = 0; k < 64; ++k) {
        float4 wv = *(const float4*)(sW + k * 64 + c4);
        float a0 = sIn[(2 * rg + 0) * 68 + k];
        float a1 = sIn[(2 * rg + 1) * 68 + k];
        acc[0][0] += a0 * wv.x; acc[0][1] += a0 * wv.y; acc[0][2] += a0 * wv.z; acc[0][3] += a0 * wv.w;
        acc[1][0] += a1 * wv.x; acc[1][1] += a1 * wv.y; acc[1][2] += a1 * wv.z; acc[1][3] += a1 * wv.w;
    }
    float scl[4], shf[4];
#pragma unroll
    for (int j = 0; j < 4; ++j) {
        int c = c4 + j;
        float sc = g1[c] * rsqrtf(v1[c] + 1e-5f);
        scl[j] = sc;
        shf[j] = be1[c] - m1[c] * sc + b1[c] * sc;
    }
    __syncthreads();   // all GEMM1 sIn/sW reads complete
#pragma unroll
    for (int i = 0; i < 2; ++i) {
        float4 z;
        z.x = fmaxf(acc[i][0] * scl[0] + shf[0], 0.f);
        z.y = fmaxf(acc[i][1] * scl[1] + shf[1], 0.f);
        z.z = fmaxf(acc[i][2] * scl[2] + shf[2], 0.f);
        z.w = fmaxf(acc[i][3] * scl[3] + shf[3], 0.f);
        *(float4*)(sIn + (2 * rg + i) * 68 + c4) = z;
    }
#pragma unroll
    for (int i = 0; i < 2; ++i)
        ((float4*)sW)[tid + 512 * i] = ((const float4*)W2)[tid + 512 * i];
    __syncthreads();

    // ---- GEMM2 ----
    float acc2[2][4] = {{0.f}};
#pragma unroll 8
    for (int k = 0; k < 64; ++k) {
        float4 wv = *(const float4*)(sW + k * 64 + c4);
        float a0 = sIn[(2 * rg + 0) * 68 + k];
        float a1 = sIn[(2 * rg + 1) * 68 + k];
        acc2[0][0] += a0 * wv.x; acc2[0][1] += a0 * wv.y; acc2[0][2] += a0 * wv.z; acc2[0][3] += a0 * wv.w;
        acc2[1][0] += a1 * wv.x; acc2[1][1] += a1 * wv.y; acc2[1][2] += a1 * wv.z; acc2[1][3] += a1 * wv.w;
    }
#pragma unroll
    for (int j = 0; j < 4; ++j) {
        int c = c4 + j;
        float sc = g2[c] * rsqrtf(v2[c] + 1e-5f);
        scl[j] = sc;
        shf[j] = be2[c] - m2[c] * sc + b2[c] * sc;
    }

    int wr0 = row0 + wave * 8;
    bool full = (wr0 + 7 < N_NODES);
    bool fast = (!last) && full && (batch_id[wr0] == batch_id[wr0 + 7]);
    float4 pacc = make_float4(0.f, 0.f, 0.f, 0.f);
#pragma unroll
    for (int r = 0; r < 2; ++r) {
        int row = row0 + rg * 2 + r;
        if (row >= N_NODES) continue;
        int b = batch_id[row];
        float4 vv = *(const float4*)(vn + b * 64 + c4);
        float4 v;
        v.x = fmaxf(acc2[r][0] * scl[0] + shf[0], 0.f) + vv.x;
        v.y = fmaxf(acc2[r][1] * scl[1] + shf[1], 0.f) + vv.y;
        v.z = fmaxf(acc2[r][2] * scl[2] + shf[2], 0.f) + vv.z;
        v.w = fmaxf(acc2[r][3] * scl[3] + shf[3], 0.f) + vv.w;
        float4 o = *(const float4*)(out + (size_t)row * 64 + c4);
        o.x += v.x; o.y += v.y; o.z += v.z; o.w += v.w;
        *(float4*)(out + (size_t)row * 64 + c4) = o;
        if (!last) {
            *(float4*)(h + (size_t)row * 64 + c4) = v;
            ushort4 rb;
            rb.x = f2bf(fmaxf(v.x, 0.f)); rb.y = f2bf(fmaxf(v.y, 0.f));
            rb.z = f2bf(fmaxf(v.z, 0.f)); rb.w = f2bf(fmaxf(v.w, 0.f));
            *(ushort4*)(rbuf_out + (size_t)row * 64 + c4) = rb;
            if (fast) {
                pacc.x += v.x; pacc.y += v.y; pacc.z += v.z; pacc.w += v.w;
            } else {
                atomicAdd(&pooled[b * 64 + c4 + 0], v.x);
                atomicAdd(&pooled[b * 64 + c4 + 1], v.y);
                atomicAdd(&pooled[b * 64 + c4 + 2], v.z);
                atomicAdd(&pooled[b * 64 + c4 + 3], v.w);
            }
        }
    }
    if (fast) {
        pacc.x += __shfl_xor(pacc.x, 16); pacc.x += __shfl_xor(pacc.x, 32);
        pacc.y += __shfl_xor(pacc.y, 16); pacc.y += __shfl_xor(pacc.y, 32);
        pacc.z += __shfl_xor(pacc.z, 16); pacc.z += __shfl_xor(pacc.z, 32);
        pacc.w += __shfl_xor(pacc.w, 16); pacc.w += __shfl_xor(pacc.w, 32);
        if ((lane >> 4) == 0) {
            int b = batch_id[wr0];
            atomicAdd(&pooled[b * 64 + c4 + 0], pacc.x);
            atomicAdd(&pooled[b * 64 + c4 + 1], pacc.y);
            atomicAdd(&pooled[b * 64 + c4 + 2], pacc.z);
            atomicAdd(&pooled[b * 64 + c4 + 3], pacc.w);
        }
    }
}

// Fused vn MLP, 1024 threads (2 rows/thread), separate kernel.
__global__ __launch_bounds__(1024) void k_vnmlp(
    const float* __restrict__ pooled_in,
    const float* __restrict__ W1, const float* __restrict__ b1,
    const float* __restrict__ g1, const float* __restrict__ be1,
    const float* __restrict__ m1, const float* __restrict__ v1,
    const float* __restrict__ W2, const float* __restrict__ b2,
    const float* __restrict__ g2, const float* __restrict__ be2,
    const float* __restrict__ m2, const float* __restrict__ v2,
    float* __restrict__ vn_out, float* __restrict__ pooled_out) {
    __shared__ float sP[128 * 68];
    __shared__ float sW[64 * 64];
    int tid = threadIdx.x;

    ((float4*)sW)[tid] = ((const float4*)W1)[tid];          // 1024 float4 exactly
#pragma unroll
    for (int i = 0; i < 2; ++i) {
        int idx = tid + 1024 * i;
        int r = idx >> 4, j = idx & 15;
        ((float4*)(sP + r * 68))[j] = ((const float4*)pooled_in)[idx];
    }
    __syncthreads();

    int c4 = (tid & 15) * 4, rg = tid >> 4;   // rg: 0..63 -> rows 2rg, 2rg+1
    float acc[2][4] = {{0.f}};
#pragma unroll 8
    for (int k = 0; k < 64; ++k) {
        float4 w = *(const float4*)(sW + k * 64 + c4);
#pragma unroll
        for (int i = 0; i < 2; ++i) {
            float a = sP[(rg * 2 + i) * 68 + k];
            acc[i][0] += a * w.x; acc[i][1] += a * w.y;
            acc[i][2] += a * w.z; acc[i][3] += a * w.w;
        }
    }
    float scl[4], shf[4];
#pragma unroll
    for (int j = 0; j < 4; ++j) {
        int c = c4 + j;
        float sc = g1[c] * rsqrtf(v1[c] + 1e-5f);
        scl[j] = sc;
        shf[j] = be1[c] - m1[c] * sc + b1[c] * sc;
    }
    __syncthreads();
#pragma unroll
    for (int i = 0; i < 2; ++i) {
        float4 z;
        z.x = fmaxf(acc[i][0] * scl[0] + shf[0], 0.f);
        z.y = fmaxf(acc[i][1] * scl[1] + shf[1], 0.f);
        z.z = fmaxf(acc[i][2] * scl[2] + shf[2], 0.f);
        z.w = fmaxf(acc[i][3] * scl[3] + shf[3], 0.f);
        *(float4*)(sP + (rg * 2 + i) * 68 + c4) = z;
    }
    ((float4*)sW)[tid] = ((const float4*)W2)[tid];
    __syncthreads();

    float acc2[2][4] = {{0.f}};
#pragma unroll 8
    for (int k = 0; k < 64; ++k) {
        float4 w = *(const float4*)(sW + k * 64 + c4);
#pragma unroll
        for (int i = 0; i < 2; ++i) {
            float a = sP[(rg * 2 + i) * 68 + k];
            acc2[i][0] += a * w.x; acc2[i][1] += a * w.y;
            acc2[i][2] += a * w.z; acc2[i][3] += a * w.w;
        }
    }
#pragma unroll
    for (int j = 0; j < 4; ++j) {
        int c = c4 + j;
        float sc = g2[c] * rsqrtf(v2[c] + 1e-5f);
        scl[j] = sc;
        shf[j] = be2[c] - m2[c] * sc + b2[c] * sc;
    }
#pragma unroll
    for (int i = 0; i < 2; ++i) {
        int row = rg * 2 + i;
        float4 o;
        o.x = fmaxf(acc2[i][0] * scl[0] + shf[0], 0.f);
        o.y = fmaxf(acc2[i][1] * scl[1] + shf[1], 0.f);
        o.z = fmaxf(acc2[i][2] * scl[2] + shf[2], 0.f);
        o.w = fmaxf(acc2[i][3] * scl[3] + shf[3], 0.f);
        *(float4*)(vn_out + row * 64 + c4) = o;
        *(float4*)(pooled_out + row * 64 + c4) = o;
    }
}

extern "C" void kernel_launch(void* const* d_in, const int* in_sizes, int n_in,
                              void* d_out, int out_size, void* d_ws, size_t ws_size,
                              hipStream_t stream) {
    const float* x      = (const float*)d_in[0];
    const float* lin_W  = (const float*)d_in[1];
    const float* lin_b  = (const float*)d_in[2];
    const float* eps    = (const float*)d_in[3];
    const float* gin_W1 = (const float*)d_in[4];
    const float* gin_b1 = (const float*)d_in[5];
    const float* gbn_g  = (const float*)d_in[6];
    const float* gbn_b  = (const float*)d_in[7];
    const float* gbn_m  = (const float*)d_in[8];
    const float* gbn_v  = (const float*)d_in[9];
    const float* gin_W2 = (const float*)d_in[10];
    const float* gin_b2 = (const float*)d_in[11];
    const float* bn_g   = (const float*)d_in[12];
    const float* bn_b   = (const float*)d_in[13];
    const float* bn_m   = (const float*)d_in[14];
    const float* bn_v   = (const float*)d_in[15];
    const float* vn_emb = (const float*)d_in[16];
    const float* vn_W1  = (const float*)d_in[17];
    const float* vn_b1  = (const float*)d_in[18];
    const float* v1g    = (const float*)d_in[19];
    const float* v1b    = (const float*)d_in[20];
    const float* v1m    = (const float*)d_in[21];
    const float* v1v    = (const float*)d_in[22];
    const float* vn_W2  = (const float*)d_in[23];
    const float* vn_b2  = (const float*)d_in[24];
    const float* v2g    = (const float*)d_in[25];
    const float* v2b    = (const float*)d_in[26];
    const float* v2m    = (const float*)d_in[27];
    const float* v2v    = (const float*)d_in[28];
    const int* src      = (const int*)d_in[29];
    const int* dst      = (const int*)d_in[30];
    const int* batch_id = (const int*)d_in[31];
    float* out = (float*)d_out;

    // workspace layout (~34 MB)
    float* h      = (float*)d_ws;                      // N*64 f32
    unsigned short* rbufA = (unsigned short*)(h + (size_t)N_NODES * 64); // N*64 bf16
    unsigned short* rbufB = rbufA + (size_t)N_NODES * 64;                // N*64 bf16
    float* vn     = (float*)(rbufB + (size_t)N_NODES * 64);              // B*64
    float* pooled = vn  + (size_t)NB * 64;             // B*64
    int*   cnt    = (int*)(pooled + (size_t)NB * 64);  // N
    unsigned short* csr_src = (unsigned short*)(cnt + N_NODES); // N*CAP ushort (8 MB)

    // ---- Bucket-CSR build: 8 sub-passes + pooled init tail ----
    hipMemsetAsync(cnt, 0, N_NODES * sizeof(int), stream);
    k_build<<<EDGE_BLOCKS * 8 + INIT_BLOCKS, 256, 0, stream>>>(src, dst, cnt, csr_src,
                                                               vn_emb, pooled);

    // input linear fused with layer-0 pre
    k_lin_pre<<<GB, 256, 0, stream>>>(x, lin_W, lin_b, vn_emb, batch_id,
                                      h, out, rbufA, pooled);

    for (int l = 0; l < 4; ++l) {
        unsigned short* rin  = (l & 1) ? rbufB : rbufA;
        unsigned short* rout = (l & 1) ? rbufA : rbufB;
        // vn MLP first: pooled(l) -> vn(l+1), pooled(l+1)-init
        k_vnmlp<<<1, 1024, 0, stream>>>(pooled,
                                        vn_W1 + l * 4096, vn_b1 + l * 64,
                                        v1g + l * 64, v1b + l * 64, v1m + l * 64, v1v + l * 64,
                                        vn_W2 + l * 4096, vn_b2 + l * 64,
                                        v2g + l * 64, v2b + l * 64, v2m + l * 64, v2v + l * 64,
                                        vn, pooled);
        k_gin<<<GB, 512, 0, stream>>>(h, eps, l, cnt, csr_src, rin,
                                      gin_W1 + l * 4096, gin_b1 + l * 64,
                                      gbn_g + l * 64, gbn_b + l * 64,
                                      gbn_m + l * 64, gbn_v + l * 64,
                                      gin_W2 + l * 4096, gin_b2 + l * 64,
                                      bn_g + l * 64, bn_b + l * 64,
                                      bn_m + l * 64, bn_v + l * 64,
                                      vn, batch_id, h, out, rout, pooled,
                                      l == 3);
    }
}